// Round 5
// baseline (588.226 us; speedup 1.0000x reference)
//
#include <hip/hip_runtime.h>
#include <stdint.h>

// Problem constants (fixed by reference)
#define M_DIM 8192   // 4 * 2048
#define N_DIM 4096   // OUT_F
#define K_DIM 4096   // IN_F
#define GS    256    // quant group size (flattened over [N][K] row-major)
#define GPR   16     // groups per output row = K/GS

// GEMM tiling: 128x128 tile, BK=64, 256 threads = 4 waves (2x2), 4x4 16x16 frags/wave
#define BM 128
#define BN 128
#define BK 64

typedef _Float16 half8 __attribute__((ext_vector_type(8)));  // 8 fp16 = 4 VGPR (MFMA A/B frag)
typedef float f32x4 __attribute__((ext_vector_type(4)));     // MFMA C/D frag

union h16cvt { _Float16 h; unsigned short u; };

__device__ __forceinline__ unsigned short f32_to_f16_bits(float f) {
  h16cvt c; c.h = (_Float16)f;  // v_cvt_f16_f32, RNE; exact for ints |n|<=2048
  return c.u;
}
__device__ __forceinline__ uint32_t pack2_f16(float a, float b) {
  return (uint32_t)f32_to_f16_bits(a) | ((uint32_t)f32_to_f16_bits(b) << 16);
}

// ---------- merged precompute: one launch, two disjoint streams ----------
// Blocks [0, WBLKS): Wq = (q - z) exact fp16, [N][K] row-major. (q-z) is an
//   integer in [-255,255] -> exact in fp16; group scale applied in the GEMM.
// Blocks [WBLKS, WBLKS+XBLKS): x fp32 -> fp16 (RNE, rel err <= 2^-11).
#define WBLKS ((N_DIM * K_DIM / 4) / 256)
#define XBLKS ((M_DIM * K_DIM / 4) / 256)

__global__ void precompute_kernel(const int* __restrict__ q,
                                  const float* __restrict__ zeros,
                                  const float* __restrict__ x,
                                  unsigned short* __restrict__ wq,
                                  unsigned short* __restrict__ xh) {
  if (blockIdx.x < WBLKS) {
    size_t idx = (size_t)blockIdx.x * 256 + threadIdx.x;  // one thread per 4 elems
    const int4 qa = reinterpret_cast<const int4*>(q)[idx];
    const float z = zeros[(idx * 4) >> 8];  // group = flat_elem/256; 4-chunk never crosses
    uint2 o;
    o.x = pack2_f16((float)qa.x - z, (float)qa.y - z);
    o.y = pack2_f16((float)qa.z - z, (float)qa.w - z);
    reinterpret_cast<uint2*>(wq)[idx] = o;
  } else {
    size_t idx = (size_t)(blockIdx.x - WBLKS) * 256 + threadIdx.x;
    float4 v = reinterpret_cast<const float4*>(x)[idx];
    uint2 o;
    o.x = pack2_f16(v.x, v.y);
    o.y = pack2_f16(v.z, v.w);
    reinterpret_cast<uint2*>(xh)[idx] = o;
  }
}

// ---------- async global->LDS, 16B/lane ----------
__device__ __forceinline__ void load_lds16(const unsigned short* g, unsigned short* l) {
  __builtin_amdgcn_global_load_lds(
      (const __attribute__((address_space(1))) uint32_t*)g,
      (__attribute__((address_space(3))) uint32_t*)l, 16, 0, 0);
}

// Stage one [128][BK] fp16 tile. LDS dest is linear (gload_lds writes base+lane*16);
// the T2 st-swizzle is applied by permuting the SOURCE k-block (b ^= row&7) and
// reading LDS with the same XOR (both-sides-or-neither rule, m201/m231).
// Result: LDS block (row, b) holds logical k-block (b ^ (row&7)).
__device__ __forceinline__ void stage_tile(const unsigned short* __restrict__ src,
                                           unsigned short* lds,
                                           int row0, int k0, int lane, int wave) {
#pragma unroll
  for (int i = 0; i < 4; ++i) {
    const int base = i * 256 + wave * 64;  // wave-uniform 16B-block index
    const int idx = base + lane;           // this lane's 16B block
    const int row = idx >> 3;              // 8 blocks (64 fp16) per row
    const int kbs = (idx & 7) ^ (row & 7); // inverse-swizzled source block
    const unsigned short* g = src + (size_t)(row0 + row) * K_DIM + k0 + kbs * 8;
    load_lds16(g, lds + (size_t)base * 8); // wave-uniform LDS base
  }
}

// ---------- main GEMM: C = X16 @ Wq^T (group-rescaled) + bias ----------
__global__ __launch_bounds__(256, 3)
void qgemm_kernel(const unsigned short* __restrict__ X16,
                  const unsigned short* __restrict__ Wq,
                  const float* __restrict__ scales,
                  const float* __restrict__ bias,
                  float* __restrict__ out) {
  __shared__ __attribute__((aligned(16))) unsigned short sA[BM * BK];
  __shared__ __attribute__((aligned(16))) unsigned short sB[BN * BK];

  const int t = threadIdx.x;
  const int lane = t & 63;
  const int wave = t >> 6;
  const int wm = wave >> 1;   // 2x2 wave grid; each wave owns 64x64 of C
  const int wn = wave & 1;
  const int cl = lane & 15;   // frag row (A) / frag col (B, C/D)
  const int kh = lane >> 4;   // lane-group 0..3

  // XCD-aware bijective swizzle (nwg=2048, %8==0)
  const int nwg = gridDim.x;
  const int bid = blockIdx.x;
  const int wg = (bid & 7) * (nwg >> 3) + (bid >> 3);
  const int tm = wg >> 5;     // wg / (N_DIM/BN=32)
  const int tn = wg & 31;
  const int m0 = tm * BM, n0 = tn * BN;

  f32x4 acc[4][4];
#pragma unroll
  for (int i = 0; i < 4; ++i)
#pragma unroll
    for (int j = 0; j < 4; ++j)
#pragma unroll
      for (int r = 0; r < 4; ++r) acc[i][j][r] = 0.0f;

  // Per-lane group scales: scale of (col, g) lives at scales[col*16 + g].
  // acc kept in units of 1/s_g; rescale by s_{g-1}/s_g at group boundaries
  // (flash-attention-style), final scale applied in the epilogue.
  const int scol = n0 + wn * 64 + cl;  // + nf*16
  float s_cur[4];
#pragma unroll
  for (int nf = 0; nf < 4; ++nf)
    s_cur[nf] = scales[(size_t)(scol + nf * 16) * GPR];

  for (int kt = 0; kt < K_DIM / BK; ++kt) {
    const int k0 = kt * BK;

    stage_tile(X16, sA, m0, k0, lane, wave);
    stage_tile(Wq,  sB, n0, k0, lane, wave);

    // Group-boundary rescale: register-only, placed BEFORE the barrier so its
    // VALU work overlaps the vmcnt drain of the staging loads.
    if ((kt > 0) && ((kt & 3) == 0)) {
      const int g = kt >> 2;
#pragma unroll
      for (int nf = 0; nf < 4; ++nf) {
        const float s_new = scales[(size_t)(scol + nf * 16) * GPR + g];
        const float r = s_cur[nf] / s_new;
        s_cur[nf] = s_new;
#pragma unroll
        for (int mf = 0; mf < 4; ++mf)
#pragma unroll
          for (int q2 = 0; q2 < 4; ++q2) acc[mf][nf][q2] *= r;
      }
    }
    __syncthreads();  // compiler emits s_waitcnt vmcnt(0) lgkmcnt(0) before s_barrier

#pragma unroll
    for (int kk = 0; kk < 2; ++kk) {
      // logical k-block kk*4+kh; stored at XOR-swizzled position (row&7 == cl&7)
      const int blk = (kk * 4 + kh) ^ (cl & 7);
      half8 av[4], bv[4];
#pragma unroll
      for (int mf = 0; mf < 4; ++mf) {
        const int row = wm * 64 + mf * 16 + cl;
        av[mf] = *reinterpret_cast<const half8*>(&sA[row * BK + blk * 8]);
      }
#pragma unroll
      for (int nf = 0; nf < 4; ++nf) {
        const int row = wn * 64 + nf * 16 + cl;
        bv[nf] = *reinterpret_cast<const half8*>(&sB[row * BK + blk * 8]);
      }
#pragma unroll
      for (int mf = 0; mf < 4; ++mf)
#pragma unroll
        for (int nf = 0; nf < 4; ++nf)
          acc[mf][nf] = __builtin_amdgcn_mfma_f32_16x16x32_f16(av[mf], bv[nf], acc[mf][nf], 0, 0, 0);
    }
    __syncthreads();  // protect LDS overwrite by next stage
  }

  // Epilogue: C = acc * s_last + bias.  C/D layout: col=lane&15, row=(lane>>4)*4+reg (m89).
#pragma unroll
  for (int nf = 0; nf < 4; ++nf) {
    const int col = scol + nf * 16;
    const float bv = bias[col];
    const float sl = s_cur[nf];
#pragma unroll
    for (int mf = 0; mf < 4; ++mf) {
      const int row = m0 + wm * 64 + mf * 16 + kh * 4;
#pragma unroll
      for (int r = 0; r < 4; ++r)
        out[(size_t)(row + r) * N_DIM + col] = acc[mf][nf][r] * sl + bv;
    }
  }
}

// ---------- fallback GEMM: zero workspace, fused dequant/convert into staging ----------
// Same tile geometry, swizzle, MFMA loop and epilogue as qgemm_kernel, but A/B are
// reg-staged (global->VGPR->cvt->ds_write_b128) so no precomputed fp16 copies needed.
__global__ __launch_bounds__(256, 2)
void qgemm_fused_kernel(const float* __restrict__ x,
                        const int* __restrict__ qw,
                        const float* __restrict__ scales,
                        const float* __restrict__ zeros,
                        const float* __restrict__ bias,
                        float* __restrict__ out) {
  __shared__ __attribute__((aligned(16))) unsigned short sA[BM * BK];
  __shared__ __attribute__((aligned(16))) unsigned short sB[BN * BK];

  const int t = threadIdx.x;
  const int lane = t & 63;
  const int wave = t >> 6;
  const int wm = wave >> 1;
  const int wn = wave & 1;
  const int cl = lane & 15;
  const int kh = lane >> 4;

  const int nwg = gridDim.x;
  const int bid = blockIdx.x;
  const int wg = (bid & 7) * (nwg >> 3) + (bid >> 3);
  const int tm = wg >> 5;
  const int tn = wg & 31;
  const int m0 = tm * BM, n0 = tn * BN;

  f32x4 acc[4][4];
#pragma unroll
  for (int i = 0; i < 4; ++i)
#pragma unroll
    for (int j = 0; j < 4; ++j)
#pragma unroll
      for (int r = 0; r < 4; ++r) acc[i][j][r] = 0.0f;

  const int scol = n0 + wn * 64 + cl;
  float s_cur[4];
#pragma unroll
  for (int nf = 0; nf < 4; ++nf)
    s_cur[nf] = scales[(size_t)(scol + nf * 16) * GPR];

  for (int kt = 0; kt < K_DIM / BK; ++kt) {
    const int k0 = kt * BK;

    // Reg-stage: issue all global loads + convert before touching LDS.
    uint4 ra[4], rb[4];
#pragma unroll
    for (int i = 0; i < 4; ++i) {
      const int idx = i * 256 + t;            // 16B dest block (linear LDS layout)
      const int row = idx >> 3;
      const int kbs = (idx & 7) ^ (row & 7);  // source-side swizzle (same as primary)
      // A: 8 fp32 -> 8 fp16
      const float4 a0 = *reinterpret_cast<const float4*>(x + (size_t)(m0 + row) * K_DIM + k0 + kbs * 8);
      const float4 a1 = *reinterpret_cast<const float4*>(x + (size_t)(m0 + row) * K_DIM + k0 + kbs * 8 + 4);
      ra[i].x = pack2_f16(a0.x, a0.y); ra[i].y = pack2_f16(a0.z, a0.w);
      ra[i].z = pack2_f16(a1.x, a1.y); ra[i].w = pack2_f16(a1.z, a1.w);
      // B: 8 int -> (q-z) fp16 (exact); 64-wide k-range never crosses a 256-group
      const int gk = k0 + kbs * 8;
      const float z = zeros[(size_t)(n0 + row) * GPR + (gk >> 8)];
      const int4 q0 = *reinterpret_cast<const int4*>(qw + (size_t)(n0 + row) * K_DIM + gk);
      const int4 q1 = *reinterpret_cast<const int4*>(qw + (size_t)(n0 + row) * K_DIM + gk + 4);
      rb[i].x = pack2_f16((float)q0.x - z, (float)q0.y - z);
      rb[i].y = pack2_f16((float)q0.z - z, (float)q0.w - z);
      rb[i].z = pack2_f16((float)q1.x - z, (float)q1.y - z);
      rb[i].w = pack2_f16((float)q1.z - z, (float)q1.w - z);
    }

    if ((kt > 0) && ((kt & 3) == 0)) {
      const int g = kt >> 2;
#pragma unroll
      for (int nf = 0; nf < 4; ++nf) {
        const float s_new = scales[(size_t)(scol + nf * 16) * GPR + g];
        const float r = s_cur[nf] / s_new;
        s_cur[nf] = s_new;
#pragma unroll
        for (int mf = 0; mf < 4; ++mf)
#pragma unroll
          for (int q2 = 0; q2 < 4; ++q2) acc[mf][nf][q2] *= r;
      }
    }

    __syncthreads();  // previous iteration's LDS reads complete
#pragma unroll
    for (int i = 0; i < 4; ++i) {
      const int idx = i * 256 + t;
      *reinterpret_cast<uint4*>(&sA[idx * 8]) = ra[i];
      *reinterpret_cast<uint4*>(&sB[idx * 8]) = rb[i];
    }
    __syncthreads();  // tiles ready

#pragma unroll
    for (int kk = 0; kk < 2; ++kk) {
      const int blk = (kk * 4 + kh) ^ (cl & 7);
      half8 av[4], bv[4];
#pragma unroll
      for (int mf = 0; mf < 4; ++mf) {
        const int row = wm * 64 + mf * 16 + cl;
        av[mf] = *reinterpret_cast<const half8*>(&sA[row * BK + blk * 8]);
      }
#pragma unroll
      for (int nf = 0; nf < 4; ++nf) {
        const int row = wn * 64 + nf * 16 + cl;
        bv[nf] = *reinterpret_cast<const half8*>(&sB[row * BK + blk * 8]);
      }
#pragma unroll
      for (int mf = 0; mf < 4; ++mf)
#pragma unroll
        for (int nf = 0; nf < 4; ++nf)
          acc[mf][nf] = __builtin_amdgcn_mfma_f32_16x16x32_f16(av[mf], bv[nf], acc[mf][nf], 0, 0, 0);
    }
  }

#pragma unroll
  for (int nf = 0; nf < 4; ++nf) {
    const int col = scol + nf * 16;
    const float bv = bias[col];
    const float sl = s_cur[nf];
#pragma unroll
    for (int mf = 0; mf < 4; ++mf) {
      const int row = m0 + wm * 64 + mf * 16 + kh * 4;
#pragma unroll
      for (int r = 0; r < 4; ++r)
        out[(size_t)(row + r) * N_DIM + col] = acc[mf][nf][r] * sl + bv;
    }
  }
}

extern "C" void kernel_launch(void* const* d_in, const int* in_sizes, int n_in,
                              void* d_out, int out_size, void* d_ws, size_t ws_size,
                              hipStream_t stream) {
  const float* x      = (const float*)d_in[0];
  const int*   qw     = (const int*)d_in[1];
  const float* scales = (const float*)d_in[2];
  const float* zeros  = (const float*)d_in[3];
  const float* bias   = (const float*)d_in[4];
  float* out = (float*)d_out;

  const size_t MiB = 1024 * 1024;
  const int ngrid = (M_DIM / BM) * (N_DIM / BN);  // 2048, %8==0 for XCD swizzle

  if (ws_size >= 96 * MiB) {
    // Fast path: precompute fp16 copies (Wq 32 MiB | X16 64 MiB), then full-rate GEMM.
    unsigned short* Wq  = (unsigned short*)d_ws;
    unsigned short* X16 = (unsigned short*)((char*)d_ws + 32 * MiB);
    precompute_kernel<<<WBLKS + XBLKS, 256, 0, stream>>>(qw, zeros, x, Wq, X16);
    qgemm_kernel<<<ngrid, 256, 0, stream>>>(X16, Wq, scales, bias, out);
  } else {
    // Insurance path: zero-workspace fused dequant GEMM (slower, always correct).
    qgemm_fused_kernel<<<ngrid, 256, 0, stream>>>(x, qw, scales, zeros, bias, out);
  }
}